// Round 15
// baseline (148.179 us; speedup 1.0000x reference)
//
#include <hip/hip_runtime.h>

typedef __attribute__((ext_vector_type(8))) short short8;
typedef __attribute__((ext_vector_type(4))) float float4_t;
typedef __attribute__((ext_vector_type(4))) unsigned int uint4_t;

#define MFMA16(A, B, C) __builtin_amdgcn_mfma_f32_16x16x32_bf16(A, B, C, 0, 0, 0)

// softmax scale * log2(e), folded into Q at QKV-epilogue time
#define QSCALE 0.1803368801111168f

__device__ __forceinline__ unsigned short f2bf(float f) {
  unsigned int u = __builtin_bit_cast(unsigned int, f);
  u += 0x7FFFu + ((u >> 16) & 1u);   // RNE
  return (unsigned short)(u >> 16);
}

__device__ __forceinline__ void gload16(const unsigned short* g, unsigned short* l) {
  __builtin_amdgcn_global_load_lds(
      (const __attribute__((address_space(1))) unsigned int*)(g),
      (__attribute__((address_space(3))) unsigned int*)(l), 16, 0, 0);
}

// ---------------- prep: x->bf16 cvt + both weight transposes ----------------
__global__ __launch_bounds__(256) void prep(
    const float* __restrict__ x, const float* __restrict__ w_qkv,
    const float* __restrict__ w_proj, unsigned short* __restrict__ xb,
    unsigned short* __restrict__ wqkvT, unsigned short* __restrict__ wprojT) {
  __shared__ unsigned short tile[32][33];
  const int bid = blockIdx.x, tid = threadIdx.x;
  if (bid < 6144) {
    const int i = bid * 256 + tid;
    float4 v = reinterpret_cast<const float4*>(x)[i];
    ushort4 r;
    r.x = f2bf(v.x); r.y = f2bf(v.y); r.z = f2bf(v.z); r.w = f2bf(v.w);
    reinterpret_cast<ushort4*>(xb)[i] = r;
    return;
  }
  const float* w; unsigned short* wT; int E, t;
  if (bid < 6576) { t = bid - 6144; w = w_qkv; wT = wqkvT; E = 1152; }
  else            { t = bid - 6576; w = w_proj; wT = wprojT; E = 384; }
  const int tiles_e = E >> 5;
  const int td = t / tiles_e, te = t - td * tiles_e;
  const int r = tid >> 3, c4 = (tid & 7) * 4;
  float4 v = *reinterpret_cast<const float4*>(&w[(size_t)(td * 32 + r) * E + te * 32 + c4]);
  tile[r][c4 + 0] = f2bf(v.x);
  tile[r][c4 + 1] = f2bf(v.y);
  tile[r][c4 + 2] = f2bf(v.z);
  tile[r][c4 + 3] = f2bf(v.w);
  __syncthreads();
  ushort4 o;
  o.x = tile[c4 + 0][r]; o.y = tile[c4 + 1][r];
  o.z = tile[c4 + 2][r]; o.w = tile[c4 + 3][r];
  *reinterpret_cast<ushort4*>(&wT[(size_t)(te * 32 + r) * 384 + td * 32 + c4]) = o;
}

// ---------------- QKV GEMM: (16384x384)@(384x1152)+bias ----------------
// BM=128, BN=64, BK=32 -> LDS 24KB (A 2x8KB + B 2x4KB) -> 6 blocks/CU (2x TLP
// vs BK=64's 3). 12 K-steps amortize prologue; same MFMA count; 64B-row
// 4-slot XOR swizzle (both-sides-consistent, G21).
__global__ __launch_bounds__(256, 6) void gemm_qkv(
    const unsigned short* __restrict__ xb,
    const unsigned short* __restrict__ wT,
    const float* __restrict__ bias,
    unsigned short* __restrict__ qb,
    unsigned short* __restrict__ kb,
    unsigned short* __restrict__ vt) {
  __shared__ alignas(16) char smem[24576];  // A:2x8KB @0, B:2x4KB @16384
  const int tid = threadIdx.x;
  const int wg = (blockIdx.x & 7) * 288 + (blockIdx.x >> 3);  // 2304 = 8 XCD x 288
  const int bm = wg / 18, bn = wg - bm * 18;
  const int m0 = bm * 128, n0 = bn * 64;
  const int lane = tid & 63, wid = tid >> 6;
  const int lr = lane & 15, lg = lane >> 4;
  const int wm = wid >> 1, wn = wid & 1;   // wave tile: 64 rows x 32 cols
  float4_t acc[4][2] = {};

  // A: 128 rows x 4 chunks(16B) = 512 -> 2/thread; B: 64 rows x 4 = 256 -> 1/thread
  const unsigned short* asrc[2];
  int adst[2];
#pragma unroll
  for (int i = 0; i < 2; ++i) {
    const int idx = tid + i * 256;
    const int r = idx >> 2, c = idx & 3;
    asrc[i] = xb + (size_t)(m0 + r) * 384 + (c ^ (r & 3)) * 8;
    adst[i] = idx * 16;
  }
  const unsigned short* bsrc;
  int bdst;
  {
    const int r = tid >> 2, c = tid & 3;
    bsrc = wT + (size_t)(n0 + r) * 384 + (c ^ (r & 3)) * 8;
    bdst = tid * 16;
  }
  const int rxor = (lr & 3) << 4;

#pragma unroll
  for (int i = 0; i < 2; ++i) gload16(asrc[i], (unsigned short*)(smem + adst[i]));
  gload16(bsrc, (unsigned short*)(smem + 16384 + bdst));
  __syncthreads();

#pragma unroll
  for (int kt = 0; kt < 12; ++kt) {
    const int cur = kt & 1;
    if (kt < 11) {
#pragma unroll
      for (int i = 0; i < 2; ++i)
        gload16(asrc[i] + (kt + 1) * 32,
                (unsigned short*)(smem + (cur ^ 1) * 8192 + adst[i]));
      gload16(bsrc + (kt + 1) * 32,
              (unsigned short*)(smem + 16384 + (cur ^ 1) * 4096 + bdst));
    }
    const char* Ab = smem + cur * 8192;
    const char* Bb = smem + 16384 + cur * 4096;
    short8 a[4], b[2];
#pragma unroll
    for (int f = 0; f < 4; ++f)
      a[f] = *reinterpret_cast<const short8*>(
          Ab + (wm * 64 + f * 16 + lr) * 64 + ((lg * 16) ^ rxor));
#pragma unroll
    for (int f = 0; f < 2; ++f)
      b[f] = *reinterpret_cast<const short8*>(
          Bb + (wn * 32 + f * 16 + lr) * 64 + ((lg * 16) ^ rxor));
    if (bn < 12) {
#pragma unroll
      for (int mf = 0; mf < 4; ++mf)
#pragma unroll
        for (int nf = 0; nf < 2; ++nf)
          acc[mf][nf] = MFMA16(b[nf], a[mf], acc[mf][nf]);  // swapped
    } else {
#pragma unroll
      for (int mf = 0; mf < 4; ++mf)
#pragma unroll
        for (int nf = 0; nf < 2; ++nf)
          acc[mf][nf] = MFMA16(a[mf], b[nf], acc[mf][nf]);
    }
    __syncthreads();
  }

  if (bn < 12) {
    const int whichk = (bn >= 6);
    unsigned short* dst = whichk ? kb : qb;
    const float sc = whichk ? 1.f : QSCALE;
#pragma unroll
    for (int nf = 0; nf < 2; ++nf) {
      const int e0 = n0 + wn * 32 + nf * 16 + lg * 4;
      const int d0 = e0 - whichk * 384;
      const int h = d0 >> 6, hi0 = d0 & 63;
      const float4 bv4 = *reinterpret_cast<const float4*>(&bias[e0]);
#pragma unroll
      for (int mf = 0; mf < 4; ++mf) {
        const int mm = m0 + wm * 64 + mf * 16 + lr;
        const int b0 = mm >> 10, n_b = mm & 1023;
        const size_t bhh = (size_t)(b0 * 6 + h);
        ushort4 sv;
        sv.x = f2bf((acc[mf][nf][0] + bv4.x) * sc);
        sv.y = f2bf((acc[mf][nf][1] + bv4.y) * sc);
        sv.z = f2bf((acc[mf][nf][2] + bv4.z) * sc);
        sv.w = f2bf((acc[mf][nf][3] + bv4.w) * sc);
        *reinterpret_cast<ushort4*>(&dst[bhh * 65536 + (size_t)n_b * 64 + hi0]) = sv;
      }
    }
  } else {
#pragma unroll
    for (int nf = 0; nf < 2; ++nf) {
      const int e = n0 + wn * 32 + nf * 16 + lr;   // [768,1152)
      const float bv = bias[e];
      const int d = e - 768;
      const int h = d >> 6, hi = d & 63;
#pragma unroll
      for (int mf = 0; mf < 4; ++mf) {
        const int mm0 = m0 + wm * 64 + mf * 16 + lg * 4;
        const int b0 = mm0 >> 10, n_b = mm0 & 1023;
        const size_t bhh = (size_t)(b0 * 6 + h);
        const int np = (n_b & ~31) | ((n_b & 12) << 1) | ((n_b & 16) >> 2);
        ushort4 sv;
        sv.x = f2bf(acc[mf][nf][0] + bv);
        sv.y = f2bf(acc[mf][nf][1] + bv);
        sv.z = f2bf(acc[mf][nf][2] + bv);
        sv.w = f2bf(acc[mf][nf][3] + bv);
        *reinterpret_cast<ushort4*>(&vt[bhh * 65536 + (size_t)hi * 1024 + np]) = sv;
      }
    }
  }
}

// ---------------- flash attention v5: 32 queries/wave (R11 verbatim) ----------------
__global__ __launch_bounds__(256, 3) void attn(
    const unsigned short* __restrict__ qb,
    const unsigned short* __restrict__ kb,
    const unsigned short* __restrict__ vt,
    unsigned short* __restrict__ ab) {
  __shared__ alignas(16) char smem[32768];  // K:[2][8KB] @0, V:[2][8KB] @16384
  const int tid = threadIdx.x;
  const int wg = (blockIdx.x & 7) * 96 + (blockIdx.x >> 3);  // XCD swizzle
  const int bh = wg >> 3, qt = wg & 7;
  const int lane = tid & 63, wid = tid >> 6;
  const int lr = lane & 15, lg = lane >> 4;
  const size_t base = (size_t)bh * 65536;
  const unsigned short* qp = qb + base;
  const unsigned short* kp = kb + base;
  const unsigned short* vp = vt + base;
  const int q0 = qt * 128 + wid * 32;

  short8 aq[2][2];   // [qf][d-half]
#pragma unroll
  for (int qf = 0; qf < 2; ++qf)
#pragma unroll
    for (int h = 0; h < 2; ++h)
      aq[qf][h] = *reinterpret_cast<const short8*>(
          &qp[(size_t)(q0 + qf * 16 + lr) * 64 + h * 32 + lg * 8]);

  const unsigned short* ksrc[2];
  const unsigned short* vsrc[2];
  int soff[2];
#pragma unroll
  for (int i = 0; i < 2; ++i) {
    const int idx = tid + i * 256;
    const int r = idx >> 3, c8 = idx & 7;
    const int cc = (c8 ^ (r & 7)) * 8;
    ksrc[i] = kp + r * 64 + cc;      // + kt*4096
    vsrc[i] = vp + r * 1024 + cc;    // + kt*64
    soff[i] = idx * 16;
  }
  const int xr = (lr & 7) << 4;

  float lsum0 = 0.f, lsum1 = 0.f;
  float4_t o0[4] = {}, o1[4] = {};

#pragma unroll
  for (int i = 0; i < 2; ++i) {
    gload16(ksrc[i], (unsigned short*)(smem + soff[i]));
    gload16(vsrc[i], (unsigned short*)(smem + 16384 + soff[i]));
  }
  __syncthreads();

  for (int kt = 0; kt < 16; ++kt) {
    const int cur = kt & 1;
    if (kt < 15) {
      const int nb = (cur ^ 1) * 8192;
#pragma unroll
      for (int i = 0; i < 2; ++i) {
        gload16(ksrc[i] + (kt + 1) * 4096, (unsigned short*)(smem + nb + soff[i]));
        gload16(vsrc[i] + (kt + 1) * 64, (unsigned short*)(smem + 16384 + nb + soff[i]));
      }
    }
    const char* kbase = smem + cur * 8192;
    const char* vbase = smem + 16384 + cur * 8192;

#pragma unroll
    for (int half = 0; half < 2; ++half) {
      short8 bk00 = *reinterpret_cast<const short8*>(
          kbase + (half * 32 + lr) * 128 + ((lg * 16) ^ xr));
      short8 bk01 = *reinterpret_cast<const short8*>(
          kbase + (half * 32 + lr) * 128 + ((64 + lg * 16) ^ xr));
      short8 bk10 = *reinterpret_cast<const short8*>(
          kbase + (half * 32 + 16 + lr) * 128 + ((lg * 16) ^ xr));
      short8 bk11 = *reinterpret_cast<const short8*>(
          kbase + (half * 32 + 16 + lr) * 128 + ((64 + lg * 16) ^ xr));
      short8 bv0 = *reinterpret_cast<const short8*>(
          vbase + (0 * 16 + lr) * 128 + ((half * 64 + lg * 16) ^ xr));
      short8 bv1 = *reinterpret_cast<const short8*>(
          vbase + (1 * 16 + lr) * 128 + ((half * 64 + lg * 16) ^ xr));
      short8 bv2 = *reinterpret_cast<const short8*>(
          vbase + (2 * 16 + lr) * 128 + ((half * 64 + lg * 16) ^ xr));
      short8 bv3 = *reinterpret_cast<const short8*>(
          vbase + (3 * 16 + lr) * 128 + ((half * 64 + lg * 16) ^ xr));

#pragma unroll
      for (int qf = 0; qf < 2; ++qf) {
        float4_t s0 = {}, s1 = {};
        __builtin_amdgcn_s_setprio(1);
        s0 = MFMA16(bk00, aq[qf][0], s0);
        s0 = MFMA16(bk01, aq[qf][1], s0);
        s1 = MFMA16(bk10, aq[qf][0], s1);
        s1 = MFMA16(bk11, aq[qf][1], s1);
        __builtin_amdgcn_s_setprio(0);

        unsigned int dw0, dw1, dw2, dw3;
        {
          const float p0 = __builtin_amdgcn_exp2f(s0[0]);
          const float p1 = __builtin_amdgcn_exp2f(s0[1]);
          const float p2 = __builtin_amdgcn_exp2f(s0[2]);
          const float p3 = __builtin_amdgcn_exp2f(s0[3]);
          asm("v_cvt_pk_bf16_f32 %0, %1, %2" : "=v"(dw0) : "v"(p0), "v"(p1));
          asm("v_cvt_pk_bf16_f32 %0, %1, %2" : "=v"(dw1) : "v"(p2), "v"(p3));
          const float p4 = __builtin_amdgcn_exp2f(s1[0]);
          const float p5 = __builtin_amdgcn_exp2f(s1[1]);
          const float p6 = __builtin_amdgcn_exp2f(s1[2]);
          const float p7 = __builtin_amdgcn_exp2f(s1[3]);
          asm("v_cvt_pk_bf16_f32 %0, %1, %2" : "=v"(dw2) : "v"(p4), "v"(p5));
          asm("v_cvt_pk_bf16_f32 %0, %1, %2" : "=v"(dw3) : "v"(p6), "v"(p7));
        }
        // consistent denominator: sum the truncated bf16 values actually used
        const float t0 = __builtin_bit_cast(float, dw0 << 16) +
                         __builtin_bit_cast(float, dw0 & 0xFFFF0000u);
        const float t1 = __builtin_bit_cast(float, dw1 << 16) +
                         __builtin_bit_cast(float, dw1 & 0xFFFF0000u);
        const float t2 = __builtin_bit_cast(float, dw2 << 16) +
                         __builtin_bit_cast(float, dw2 & 0xFFFF0000u);
        const float t3 = __builtin_bit_cast(float, dw3 << 16) +
                         __builtin_bit_cast(float, dw3 & 0xFFFF0000u);
        if (qf == 0) lsum0 += (t0 + t1) + (t2 + t3);
        else         lsum1 += (t0 + t1) + (t2 + t3);

        uint4_t pw;
        pw[0] = dw0; pw[1] = dw1; pw[2] = dw2; pw[3] = dw3;
        const short8 pa = __builtin_bit_cast(short8, pw);
        float4_t* o = (qf == 0) ? o0 : o1;   // compile-time after unroll
        __builtin_amdgcn_s_setprio(1);
        o[0] = MFMA16(pa, bv0, o[0]);
        o[1] = MFMA16(pa, bv1, o[1]);
        o[2] = MFMA16(pa, bv2, o[2]);
        o[3] = MFMA16(pa, bv3, o[3]);
        __builtin_amdgcn_s_setprio(0);
      }
    }
    __syncthreads();
  }

  float ti0 = lsum0, ti1 = lsum1;
  ti0 += __shfl_xor(ti0, 16);
  ti0 += __shfl_xor(ti0, 32);
  ti1 += __shfl_xor(ti1, 16);
  ti1 += __shfl_xor(ti1, 32);
  const float inv0 = 1.f / ti0;
  const float inv1 = 1.f / ti1;

  const int b = bh / 6, h = bh - b * 6;
#pragma unroll
  for (int qf = 0; qf < 2; ++qf) {
    const float4_t* o = (qf == 0) ? o0 : o1;
    const float inv = (qf == 0) ? inv0 : inv1;
    float invj[4];
#pragma unroll
    for (int j = 0; j < 4; ++j)
      invj[j] = __shfl(inv, lg * 4 + j);
#pragma unroll
    for (int f = 0; f < 4; ++f)
#pragma unroll
      for (int j = 0; j < 4; ++j) {
        const int q = q0 + qf * 16 + lg * 4 + j;
        ab[(size_t)(b * 1024 + q) * 384 + h * 64 + f * 16 + lr] =
            f2bf(o[f][j] * invj[j]);
      }
  }
}

// ---------------- proj GEMM: (16384x384)@(384x384)+bias -> fp32 ----------------
__global__ __launch_bounds__(256, 3) void gemm_proj(
    const unsigned short* __restrict__ ab,
    const unsigned short* __restrict__ wT,
    const float* __restrict__ bias,
    float* __restrict__ out) {
  __shared__ alignas(16) char smem[49152];  // A:2x8KB @0, B:2x16KB @16384
  const int tid = threadIdx.x;
  const int wg = (blockIdx.x & 7) * 96 + (blockIdx.x >> 3);
  const int bm = wg / 3, bn = wg - bm * 3;
  const int m0 = bm * 64, n0 = bn * 128;
  const int lane = tid & 63, wid = tid >> 6;
  const int lr = lane & 15, lg = lane >> 4;
  const int wm = wid >> 1, wn = wid & 1;
  float4_t acc[2][4] = {};

  const unsigned short* asrc[2];
  const unsigned short* bsrc[4];
  int adst[2], bdst[4];
#pragma unroll
  for (int i = 0; i < 2; ++i) {
    const int idx = tid + i * 256;
    const int r = idx >> 3, c8 = idx & 7;
    asrc[i] = ab + (size_t)(m0 + r) * 384 + (c8 ^ (r & 7)) * 8;
    adst[i] = idx * 16;
  }
#pragma unroll
  for (int i = 0; i < 4; ++i) {
    const int idx = tid + i * 256;
    const int r = idx >> 3, c8 = idx & 7;
    bsrc[i] = wT + (size_t)(n0 + r) * 384 + (c8 ^ (r & 7)) * 8;
    bdst[i] = idx * 16;
  }
  const int rxor = (lr & 7) << 4;

#pragma unroll
  for (int i = 0; i < 2; ++i) gload16(asrc[i], (unsigned short*)(smem + adst[i]));
#pragma unroll
  for (int i = 0; i < 4; ++i) gload16(bsrc[i], (unsigned short*)(smem + 16384 + bdst[i]));
  __syncthreads();

#pragma unroll
  for (int kt = 0; kt < 6; ++kt) {
    const int cur = kt & 1;
    if (kt < 5) {
#pragma unroll
      for (int i = 0; i < 2; ++i)
        gload16(asrc[i] + (kt + 1) * 64, (unsigned short*)(smem + (cur ^ 1) * 8192 + adst[i]));
#pragma unroll
      for (int i = 0; i < 4; ++i)
        gload16(bsrc[i] + (kt + 1) * 64, (unsigned short*)(smem + 16384 + (cur ^ 1) * 16384 + bdst[i]));
    }
    const char* Ab = smem + cur * 8192;
    const char* Bb = smem + 16384 + cur * 16384;
#pragma unroll
    for (int kk = 0; kk < 2; ++kk) {
      short8 a[2], b[4];
#pragma unroll
      for (int f = 0; f < 2; ++f)
        a[f] = *reinterpret_cast<const short8*>(
            Ab + (wm * 32 + f * 16 + lr) * 128 + ((kk * 64 + lg * 16) ^ rxor));
#pragma unroll
      for (int f = 0; f < 4; ++f)
        b[f] = *reinterpret_cast<const short8*>(
            Bb + (wn * 64 + f * 16 + lr) * 128 + ((kk * 64 + lg * 16) ^ rxor));
#pragma unroll
      for (int mf = 0; mf < 2; ++mf)
#pragma unroll
        for (int nf = 0; nf < 4; ++nf)
          acc[mf][nf] = MFMA16(b[nf], a[mf], acc[mf][nf]);  // swapped
    }
    __syncthreads();
  }

#pragma unroll
  for (int nf = 0; nf < 4; ++nf) {
    const int e0 = n0 + wn * 64 + nf * 16 + lg * 4;
    const float4 bv4 = *reinterpret_cast<const float4*>(&bias[e0]);
#pragma unroll
    for (int mf = 0; mf < 2; ++mf) {
      const int mm = m0 + wm * 32 + mf * 16 + lr;
      float4 ov;
      ov.x = acc[mf][nf][0] + bv4.x;
      ov.y = acc[mf][nf][1] + bv4.y;
      ov.z = acc[mf][nf][2] + bv4.z;
      ov.w = acc[mf][nf][3] + bv4.w;
      *reinterpret_cast<float4*>(&out[(size_t)mm * 384 + e0]) = ov;
    }
  }
}

extern "C" void kernel_launch(void* const* d_in, const int* in_sizes, int n_in,
                              void* d_out, int out_size, void* d_ws, size_t ws_size,
                              hipStream_t stream) {
  const float* x      = (const float*)d_in[0];
  const float* w_qkv  = (const float*)d_in[1];
  const float* b_qkv  = (const float*)d_in[2];
  const float* w_proj = (const float*)d_in[3];
  const float* b_proj = (const float*)d_in[4];
  float* out = (float*)d_out;

  char* ws = (char*)d_ws;
  unsigned short* xb     = (unsigned short*)(ws);               // 12,582,912 B
  unsigned short* wqkvT  = (unsigned short*)(ws + 12582912);    //    884,736 B
  unsigned short* wprojT = (unsigned short*)(ws + 13467648);    //    294,912 B
  unsigned short* qb     = (unsigned short*)(ws + 13762560);    // 12,582,912 B
  unsigned short* kb     = (unsigned short*)(ws + 26345472);    // 12,582,912 B
  unsigned short* vt     = (unsigned short*)(ws + 38928384);    // 12,582,912 B
  unsigned short* ab     = xb;  // xb is dead after gemm_qkv; reuse for attn out

  prep<<<6720, 256, 0, stream>>>(x, w_qkv, w_proj, xb, wqkvT, wprojT);
  gemm_qkv<<<2304, 256, 0, stream>>>(xb, wqkvT, b_qkv, qb, kb, vt);
  attn<<<768, 256, 0, stream>>>(qb, kb, vt, ab);
  gemm_proj<<<768, 256, 0, stream>>>(ab, wprojT, b_proj, out);
}

// Round 16
// 85.633 us; speedup vs baseline: 1.7304x; 1.7304x over previous
//
#include <hip/hip_runtime.h>

typedef __attribute__((ext_vector_type(8))) short short8;
typedef __attribute__((ext_vector_type(4))) float float4_t;
typedef __attribute__((ext_vector_type(4))) unsigned int uint4_t;

#define MFMA16(A, B, C) __builtin_amdgcn_mfma_f32_16x16x32_bf16(A, B, C, 0, 0, 0)

// softmax scale * log2(e), folded into Q at QKV-epilogue time
#define QSCALE 0.1803368801111168f

__device__ __forceinline__ unsigned short f2bf(float f) {
  unsigned int u = __builtin_bit_cast(unsigned int, f);
  u += 0x7FFFu + ((u >> 16) & 1u);   // RNE
  return (unsigned short)(u >> 16);
}

__device__ __forceinline__ void gload16(const unsigned short* g, unsigned short* l) {
  __builtin_amdgcn_global_load_lds(
      (const __attribute__((address_space(1))) unsigned int*)(g),
      (__attribute__((address_space(3))) unsigned int*)(l), 16, 0, 0);
}

// ---------------- prep: x->bf16 cvt + both weight transposes ----------------
__global__ __launch_bounds__(256) void prep(
    const float* __restrict__ x, const float* __restrict__ w_qkv,
    const float* __restrict__ w_proj, unsigned short* __restrict__ xb,
    unsigned short* __restrict__ wqkvT, unsigned short* __restrict__ wprojT) {
  __shared__ unsigned short tile[32][33];
  const int bid = blockIdx.x, tid = threadIdx.x;
  if (bid < 6144) {
    const int i = bid * 256 + tid;
    float4 v = reinterpret_cast<const float4*>(x)[i];
    ushort4 r;
    r.x = f2bf(v.x); r.y = f2bf(v.y); r.z = f2bf(v.z); r.w = f2bf(v.w);
    reinterpret_cast<ushort4*>(xb)[i] = r;
    return;
  }
  const float* w; unsigned short* wT; int E, t;
  if (bid < 6576) { t = bid - 6144; w = w_qkv; wT = wqkvT; E = 1152; }
  else            { t = bid - 6576; w = w_proj; wT = wprojT; E = 384; }
  const int tiles_e = E >> 5;
  const int td = t / tiles_e, te = t - td * tiles_e;
  const int r = tid >> 3, c4 = (tid & 7) * 4;
  float4 v = *reinterpret_cast<const float4*>(&w[(size_t)(td * 32 + r) * E + te * 32 + c4]);
  tile[r][c4 + 0] = f2bf(v.x);
  tile[r][c4 + 1] = f2bf(v.y);
  tile[r][c4 + 2] = f2bf(v.z);
  tile[r][c4 + 3] = f2bf(v.w);
  __syncthreads();
  ushort4 o;
  o.x = tile[c4 + 0][r]; o.y = tile[c4 + 1][r];
  o.z = tile[c4 + 2][r]; o.w = tile[c4 + 3][r];
  *reinterpret_cast<ushort4*>(&wT[(size_t)(te * 32 + r) * 384 + td * 32 + c4]) = o;
}

// ---------------- QKV GEMM: (16384x384)@(384x1152)+bias ----------------
// BM=128, BN=64, BK=64; LDS 48KB; 3 blocks/CU. q/k blocks (bn<12) use SWAPPED
// mfma operands (D: row=feature, col=token) -> ushort4 stores; v blocks keep
// original order (np-permuted store already vec4).
__global__ __launch_bounds__(256, 3) void gemm_qkv(
    const unsigned short* __restrict__ xb,
    const unsigned short* __restrict__ wT,
    const float* __restrict__ bias,
    unsigned short* __restrict__ qb,
    unsigned short* __restrict__ kb,
    unsigned short* __restrict__ vt) {
  __shared__ alignas(16) char smem[49152];  // A:2x16KB @0, B:2x8KB @32768
  const int tid = threadIdx.x;
  const int wg = (blockIdx.x & 7) * 288 + (blockIdx.x >> 3);  // 2304 = 8 XCD x 288
  const int bm = wg / 18, bn = wg - bm * 18;
  const int m0 = bm * 128, n0 = bn * 64;
  const int lane = tid & 63, wid = tid >> 6;
  const int lr = lane & 15, lg = lane >> 4;
  const int wm = wid >> 1, wn = wid & 1;   // wave tile: 64 rows x 32 cols
  float4_t acc[4][2] = {};

  const unsigned short* asrc[4];
  const unsigned short* bsrc[2];
  int adst[4], bdst[2];
#pragma unroll
  for (int i = 0; i < 4; ++i) {
    const int idx = tid + i * 256;
    const int r = idx >> 3, c8 = idx & 7;
    asrc[i] = xb + (size_t)(m0 + r) * 384 + (c8 ^ (r & 7)) * 8;
    adst[i] = idx * 16;
  }
#pragma unroll
  for (int i = 0; i < 2; ++i) {
    const int idx = tid + i * 256;
    const int r = idx >> 3, c8 = idx & 7;
    bsrc[i] = wT + (size_t)(n0 + r) * 384 + (c8 ^ (r & 7)) * 8;
    bdst[i] = idx * 16;
  }
  const int rxor = (lr & 7) << 4;

#pragma unroll
  for (int i = 0; i < 4; ++i) gload16(asrc[i], (unsigned short*)(smem + adst[i]));
#pragma unroll
  for (int i = 0; i < 2; ++i) gload16(bsrc[i], (unsigned short*)(smem + 32768 + bdst[i]));
  __syncthreads();

#pragma unroll
  for (int kt = 0; kt < 6; ++kt) {
    const int cur = kt & 1;
    if (kt < 5) {
#pragma unroll
      for (int i = 0; i < 4; ++i)
        gload16(asrc[i] + (kt + 1) * 64,
                (unsigned short*)(smem + (cur ^ 1) * 16384 + adst[i]));
#pragma unroll
      for (int i = 0; i < 2; ++i)
        gload16(bsrc[i] + (kt + 1) * 64,
                (unsigned short*)(smem + 32768 + (cur ^ 1) * 8192 + bdst[i]));
    }
    const char* Ab = smem + cur * 16384;
    const char* Bb = smem + 32768 + cur * 8192;
#pragma unroll
    for (int kk = 0; kk < 2; ++kk) {
      short8 a[4], b[2];
#pragma unroll
      for (int f = 0; f < 4; ++f)
        a[f] = *reinterpret_cast<const short8*>(
            Ab + (wm * 64 + f * 16 + lr) * 128 + ((kk * 64 + lg * 16) ^ rxor));
#pragma unroll
      for (int f = 0; f < 2; ++f)
        b[f] = *reinterpret_cast<const short8*>(
            Bb + (wn * 32 + f * 16 + lr) * 128 + ((kk * 64 + lg * 16) ^ rxor));
      if (bn < 12) {
#pragma unroll
        for (int mf = 0; mf < 4; ++mf)
#pragma unroll
          for (int nf = 0; nf < 2; ++nf)
            acc[mf][nf] = MFMA16(b[nf], a[mf], acc[mf][nf]);  // swapped
      } else {
#pragma unroll
        for (int mf = 0; mf < 4; ++mf)
#pragma unroll
          for (int nf = 0; nf < 2; ++nf)
            acc[mf][nf] = MFMA16(a[mf], b[nf], acc[mf][nf]);
      }
    }
    __syncthreads();
  }

  if (bn < 12) {
    const int whichk = (bn >= 6);
    unsigned short* dst = whichk ? kb : qb;
    const float sc = whichk ? 1.f : QSCALE;
#pragma unroll
    for (int nf = 0; nf < 2; ++nf) {
      const int e0 = n0 + wn * 32 + nf * 16 + lg * 4;
      const int d0 = e0 - whichk * 384;
      const int h = d0 >> 6, hi0 = d0 & 63;
      const float4 bv4 = *reinterpret_cast<const float4*>(&bias[e0]);
#pragma unroll
      for (int mf = 0; mf < 4; ++mf) {
        const int mm = m0 + wm * 64 + mf * 16 + lr;
        const int b0 = mm >> 10, n_b = mm & 1023;
        const size_t bhh = (size_t)(b0 * 6 + h);
        ushort4 sv;
        sv.x = f2bf((acc[mf][nf][0] + bv4.x) * sc);
        sv.y = f2bf((acc[mf][nf][1] + bv4.y) * sc);
        sv.z = f2bf((acc[mf][nf][2] + bv4.z) * sc);
        sv.w = f2bf((acc[mf][nf][3] + bv4.w) * sc);
        *reinterpret_cast<ushort4*>(&dst[bhh * 65536 + (size_t)n_b * 64 + hi0]) = sv;
      }
    }
  } else {
#pragma unroll
    for (int nf = 0; nf < 2; ++nf) {
      const int e = n0 + wn * 32 + nf * 16 + lr;   // [768,1152)
      const float bv = bias[e];
      const int d = e - 768;
      const int h = d >> 6, hi = d & 63;
#pragma unroll
      for (int mf = 0; mf < 4; ++mf) {
        const int mm0 = m0 + wm * 64 + mf * 16 + lg * 4;
        const int b0 = mm0 >> 10, n_b = mm0 & 1023;
        const size_t bhh = (size_t)(b0 * 6 + h);
        const int np = (n_b & ~31) | ((n_b & 12) << 1) | ((n_b & 16) >> 2);
        ushort4 sv;
        sv.x = f2bf(acc[mf][nf][0] + bv);
        sv.y = f2bf(acc[mf][nf][1] + bv);
        sv.z = f2bf(acc[mf][nf][2] + bv);
        sv.w = f2bf(acc[mf][nf][3] + bv);
        *reinterpret_cast<ushort4*>(&vt[bhh * 65536 + (size_t)hi * 1024 + np]) = sv;
      }
    }
  }
}

// ---------------- flash attention v5: 32 queries/wave ----------------
// grid = 96 (b,h) x 8 q-tiles of 128; 4 waves x 32 queries; 3 blocks/CU.
// Per-tile LDS reads are independent of the wave's query count, so 32q/wave
// amortizes K/V fragment reads over 2x MFMA vs 16q/wave.
__global__ __launch_bounds__(256, 3) void attn(
    const unsigned short* __restrict__ qb,
    const unsigned short* __restrict__ kb,
    const unsigned short* __restrict__ vt,
    unsigned short* __restrict__ ab) {
  __shared__ alignas(16) char smem[32768];  // K:[2][8KB] @0, V:[2][8KB] @16384
  const int tid = threadIdx.x;
  const int wg = (blockIdx.x & 7) * 96 + (blockIdx.x >> 3);  // XCD swizzle
  const int bh = wg >> 3, qt = wg & 7;
  const int lane = tid & 63, wid = tid >> 6;
  const int lr = lane & 15, lg = lane >> 4;
  const size_t base = (size_t)bh * 65536;
  const unsigned short* qp = qb + base;
  const unsigned short* kp = kb + base;
  const unsigned short* vp = vt + base;
  const int q0 = qt * 128 + wid * 32;

  short8 aq[2][2];   // [qf][d-half]
#pragma unroll
  for (int qf = 0; qf < 2; ++qf)
#pragma unroll
    for (int h = 0; h < 2; ++h)
      aq[qf][h] = *reinterpret_cast<const short8*>(
          &qp[(size_t)(q0 + qf * 16 + lr) * 64 + h * 32 + lg * 8]);

  const unsigned short* ksrc[2];
  const unsigned short* vsrc[2];
  int soff[2];
#pragma unroll
  for (int i = 0; i < 2; ++i) {
    const int idx = tid + i * 256;
    const int r = idx >> 3, c8 = idx & 7;
    const int cc = (c8 ^ (r & 7)) * 8;
    ksrc[i] = kp + r * 64 + cc;      // + kt*4096
    vsrc[i] = vp + r * 1024 + cc;    // + kt*64
    soff[i] = idx * 16;
  }
  const int xr = (lr & 7) << 4;

  float lsum0 = 0.f, lsum1 = 0.f;
  float4_t o0[4] = {}, o1[4] = {};

#pragma unroll
  for (int i = 0; i < 2; ++i) {
    gload16(ksrc[i], (unsigned short*)(smem + soff[i]));
    gload16(vsrc[i], (unsigned short*)(smem + 16384 + soff[i]));
  }
  __syncthreads();

  for (int kt = 0; kt < 16; ++kt) {
    const int cur = kt & 1;
    if (kt < 15) {
      const int nb = (cur ^ 1) * 8192;
#pragma unroll
      for (int i = 0; i < 2; ++i) {
        gload16(ksrc[i] + (kt + 1) * 4096, (unsigned short*)(smem + nb + soff[i]));
        gload16(vsrc[i] + (kt + 1) * 64, (unsigned short*)(smem + 16384 + nb + soff[i]));
      }
    }
    const char* kbase = smem + cur * 8192;
    const char* vbase = smem + 16384 + cur * 8192;

#pragma unroll
    for (int half = 0; half < 2; ++half) {
      short8 bk00 = *reinterpret_cast<const short8*>(
          kbase + (half * 32 + lr) * 128 + ((lg * 16) ^ xr));
      short8 bk01 = *reinterpret_cast<const short8*>(
          kbase + (half * 32 + lr) * 128 + ((64 + lg * 16) ^ xr));
      short8 bk10 = *reinterpret_cast<const short8*>(
          kbase + (half * 32 + 16 + lr) * 128 + ((lg * 16) ^ xr));
      short8 bk11 = *reinterpret_cast<const short8*>(
          kbase + (half * 32 + 16 + lr) * 128 + ((64 + lg * 16) ^ xr));
      short8 bv0 = *reinterpret_cast<const short8*>(
          vbase + (0 * 16 + lr) * 128 + ((half * 64 + lg * 16) ^ xr));
      short8 bv1 = *reinterpret_cast<const short8*>(
          vbase + (1 * 16 + lr) * 128 + ((half * 64 + lg * 16) ^ xr));
      short8 bv2 = *reinterpret_cast<const short8*>(
          vbase + (2 * 16 + lr) * 128 + ((half * 64 + lg * 16) ^ xr));
      short8 bv3 = *reinterpret_cast<const short8*>(
          vbase + (3 * 16 + lr) * 128 + ((half * 64 + lg * 16) ^ xr));

#pragma unroll
      for (int qf = 0; qf < 2; ++qf) {
        float4_t s0 = {}, s1 = {};
        __builtin_amdgcn_s_setprio(1);
        s0 = MFMA16(bk00, aq[qf][0], s0);
        s0 = MFMA16(bk01, aq[qf][1], s0);
        s1 = MFMA16(bk10, aq[qf][0], s1);
        s1 = MFMA16(bk11, aq[qf][1], s1);
        __builtin_amdgcn_s_setprio(0);

        unsigned int dw0, dw1, dw2, dw3;
        {
          const float p0 = __builtin_amdgcn_exp2f(s0[0]);
          const float p1 = __builtin_amdgcn_exp2f(s0[1]);
          const float p2 = __builtin_amdgcn_exp2f(s0[2]);
          const float p3 = __builtin_amdgcn_exp2f(s0[3]);
          asm("v_cvt_pk_bf16_f32 %0, %1, %2" : "=v"(dw0) : "v"(p0), "v"(p1));
          asm("v_cvt_pk_bf16_f32 %0, %1, %2" : "=v"(dw1) : "v"(p2), "v"(p3));
          const float p4 = __builtin_amdgcn_exp2f(s1[0]);
          const float p5 = __builtin_amdgcn_exp2f(s1[1]);
          const float p6 = __builtin_amdgcn_exp2f(s1[2]);
          const float p7 = __builtin_amdgcn_exp2f(s1[3]);
          asm("v_cvt_pk_bf16_f32 %0, %1, %2" : "=v"(dw2) : "v"(p4), "v"(p5));
          asm("v_cvt_pk_bf16_f32 %0, %1, %2" : "=v"(dw3) : "v"(p6), "v"(p7));
        }
        // consistent denominator: sum the truncated bf16 values actually used
        const float t0 = __builtin_bit_cast(float, dw0 << 16) +
                         __builtin_bit_cast(float, dw0 & 0xFFFF0000u);
        const float t1 = __builtin_bit_cast(float, dw1 << 16) +
                         __builtin_bit_cast(float, dw1 & 0xFFFF0000u);
        const float t2 = __builtin_bit_cast(float, dw2 << 16) +
                         __builtin_bit_cast(float, dw2 & 0xFFFF0000u);
        const float t3 = __builtin_bit_cast(float, dw3 << 16) +
                         __builtin_bit_cast(float, dw3 & 0xFFFF0000u);
        if (qf == 0) lsum0 += (t0 + t1) + (t2 + t3);
        else         lsum1 += (t0 + t1) + (t2 + t3);

        uint4_t pw;
        pw[0] = dw0; pw[1] = dw1; pw[2] = dw2; pw[3] = dw3;
        const short8 pa = __builtin_bit_cast(short8, pw);
        float4_t* o = (qf == 0) ? o0 : o1;   // compile-time after unroll
        __builtin_amdgcn_s_setprio(1);
        o[0] = MFMA16(pa, bv0, o[0]);
        o[1] = MFMA16(pa, bv1, o[1]);
        o[2] = MFMA16(pa, bv2, o[2]);
        o[3] = MFMA16(pa, bv3, o[3]);
        __builtin_amdgcn_s_setprio(0);
      }
    }
    __syncthreads();
  }

  float ti0 = lsum0, ti1 = lsum1;
  ti0 += __shfl_xor(ti0, 16);
  ti0 += __shfl_xor(ti0, 32);
  ti1 += __shfl_xor(ti1, 16);
  ti1 += __shfl_xor(ti1, 32);
  const float inv0 = 1.f / ti0;
  const float inv1 = 1.f / ti1;

  const int b = bh / 6, h = bh - b * 6;
#pragma unroll
  for (int qf = 0; qf < 2; ++qf) {
    const float4_t* o = (qf == 0) ? o0 : o1;
    const float inv = (qf == 0) ? inv0 : inv1;
    float invj[4];
#pragma unroll
    for (int j = 0; j < 4; ++j)
      invj[j] = __shfl(inv, lg * 4 + j);
#pragma unroll
    for (int f = 0; f < 4; ++f)
#pragma unroll
      for (int j = 0; j < 4; ++j) {
        const int q = q0 + qf * 16 + lg * 4 + j;
        ab[(size_t)(b * 1024 + q) * 384 + h * 64 + f * 16 + lr] =
            f2bf(o[f][j] * invj[j]);
      }
  }
}

// ---------------- proj GEMM: (16384x384)@(384x384)+bias -> fp32 ----------------
__global__ __launch_bounds__(256, 3) void gemm_proj(
    const unsigned short* __restrict__ ab,
    const unsigned short* __restrict__ wT,
    const float* __restrict__ bias,
    float* __restrict__ out) {
  __shared__ alignas(16) char smem[49152];  // A:2x8KB @0, B:2x16KB @16384
  const int tid = threadIdx.x;
  const int wg = (blockIdx.x & 7) * 96 + (blockIdx.x >> 3);
  const int bm = wg / 3, bn = wg - bm * 3;
  const int m0 = bm * 64, n0 = bn * 128;
  const int lane = tid & 63, wid = tid >> 6;
  const int lr = lane & 15, lg = lane >> 4;
  const int wm = wid >> 1, wn = wid & 1;
  float4_t acc[2][4] = {};

  const unsigned short* asrc[2];
  const unsigned short* bsrc[4];
  int adst[2], bdst[4];
#pragma unroll
  for (int i = 0; i < 2; ++i) {
    const int idx = tid + i * 256;
    const int r = idx >> 3, c8 = idx & 7;
    asrc[i] = ab + (size_t)(m0 + r) * 384 + (c8 ^ (r & 7)) * 8;
    adst[i] = idx * 16;
  }
#pragma unroll
  for (int i = 0; i < 4; ++i) {
    const int idx = tid + i * 256;
    const int r = idx >> 3, c8 = idx & 7;
    bsrc[i] = wT + (size_t)(n0 + r) * 384 + (c8 ^ (r & 7)) * 8;
    bdst[i] = idx * 16;
  }
  const int rxor = (lr & 7) << 4;

#pragma unroll
  for (int i = 0; i < 2; ++i) gload16(asrc[i], (unsigned short*)(smem + adst[i]));
#pragma unroll
  for (int i = 0; i < 4; ++i) gload16(bsrc[i], (unsigned short*)(smem + 16384 + bdst[i]));
  __syncthreads();

#pragma unroll
  for (int kt = 0; kt < 6; ++kt) {
    const int cur = kt & 1;
    if (kt < 5) {
#pragma unroll
      for (int i = 0; i < 2; ++i)
        gload16(asrc[i] + (kt + 1) * 64, (unsigned short*)(smem + (cur ^ 1) * 8192 + adst[i]));
#pragma unroll
      for (int i = 0; i < 4; ++i)
        gload16(bsrc[i] + (kt + 1) * 64, (unsigned short*)(smem + 16384 + (cur ^ 1) * 16384 + bdst[i]));
    }
    const char* Ab = smem + cur * 8192;
    const char* Bb = smem + 16384 + cur * 16384;
#pragma unroll
    for (int kk = 0; kk < 2; ++kk) {
      short8 a[2], b[4];
#pragma unroll
      for (int f = 0; f < 2; ++f)
        a[f] = *reinterpret_cast<const short8*>(
            Ab + (wm * 32 + f * 16 + lr) * 128 + ((kk * 64 + lg * 16) ^ rxor));
#pragma unroll
      for (int f = 0; f < 4; ++f)
        b[f] = *reinterpret_cast<const short8*>(
            Bb + (wn * 64 + f * 16 + lr) * 128 + ((kk * 64 + lg * 16) ^ rxor));
#pragma unroll
      for (int mf = 0; mf < 2; ++mf)
#pragma unroll
        for (int nf = 0; nf < 4; ++nf)
          acc[mf][nf] = MFMA16(b[nf], a[mf], acc[mf][nf]);  // swapped
    }
    __syncthreads();
  }

#pragma unroll
  for (int nf = 0; nf < 4; ++nf) {
    const int e0 = n0 + wn * 64 + nf * 16 + lg * 4;
    const float4 bv4 = *reinterpret_cast<const float4*>(&bias[e0]);
#pragma unroll
    for (int mf = 0; mf < 2; ++mf) {
      const int mm = m0 + wm * 32 + mf * 16 + lr;
      float4 ov;
      ov.x = acc[mf][nf][0] + bv4.x;
      ov.y = acc[mf][nf][1] + bv4.y;
      ov.z = acc[mf][nf][2] + bv4.z;
      ov.w = acc[mf][nf][3] + bv4.w;
      *reinterpret_cast<float4*>(&out[(size_t)mm * 384 + e0]) = ov;
    }
  }
}

extern "C" void kernel_launch(void* const* d_in, const int* in_sizes, int n_in,
                              void* d_out, int out_size, void* d_ws, size_t ws_size,
                              hipStream_t stream) {
  const float* x      = (const float*)d_in[0];
  const float* w_qkv  = (const float*)d_in[1];
  const float* b_qkv  = (const float*)d_in[2];
  const float* w_proj = (const float*)d_in[3];
  const float* b_proj = (const float*)d_in[4];
  float* out = (float*)d_out;

  char* ws = (char*)d_ws;
  unsigned short* xb     = (unsigned short*)(ws);               // 12,582,912 B
  unsigned short* wqkvT  = (unsigned short*)(ws + 12582912);    //    884,736 B
  unsigned short* wprojT = (unsigned short*)(ws + 13467648);    //    294,912 B
  unsigned short* qb     = (unsigned short*)(ws + 13762560);    // 12,582,912 B
  unsigned short* kb     = (unsigned short*)(ws + 26345472);    // 12,582,912 B
  unsigned short* vt     = (unsigned short*)(ws + 38928384);    // 12,582,912 B
  unsigned short* ab     = xb;  // xb is dead after gemm_qkv; reuse for attn out

  prep<<<6720, 256, 0, stream>>>(x, w_qkv, w_proj, xb, wqkvT, wprojT);
  gemm_qkv<<<2304, 256, 0, stream>>>(xb, wqkvT, b_qkv, qb, kb, vt);
  attn<<<768, 256, 0, stream>>>(qb, kb, vt, ab);
  gemm_proj<<<768, 256, 0, stream>>>(ab, wprojT, b_proj, out);
}